// Round 15
// baseline (155.635 us; speedup 1.0000x reference)
//
#include <hip/hip_runtime.h>
#include <math.h>

// N=8192, D=256. sim = normed @ normed^T; four reductions fused, sim never materialized.
// H-only fp16 (K=256): drops terms bounded ~5e-4 (verified absmax 0.0 r2-r12).
// r13: NO LDS staging — A2 is 4 MB (L2/L3-resident); waves load MFMA fragments
// directly global->VGPR (lesson #7: staging cache-fit data is pure overhead).
// No barriers in the K-loop; occupancy (12 waves/CU) hides latency via TLP (m114),
// which r12 proved per-wave queue depth cannot.
#define NROWS 8192
#define DIM   256
#define K2    256                  // fp16 elems per row (512 B)
#define NTB   64                   // 8192/128 tiles per side
#define NTRI  2080                 // NTB*(NTB+1)/2 lower-tri tiles; 2080 = 8*260
#define SIM_THR 0.85f

#define A2_OFF   1024
#define EDGE_OFF (1024 + NROWS * K2 * 2)

typedef _Float16 half8 __attribute__((ext_vector_type(8)));
typedef float f32x4 __attribute__((ext_vector_type(4)));

__device__ inline void atomicMaxF(float* addr, float val) {
    if (val >= 0.f) atomicMax((int*)addr, __float_as_int(val));
    else            atomicMin((unsigned int*)addr, __float_as_uint(val));
}

// One wave per row: normalize (fp32), round to fp16, write H (8192 x 256 fp16).
__global__ __launch_bounds__(256) void prep_kernel(const float* __restrict__ x,
                                                   unsigned short* __restrict__ a2,
                                                   float* wsf) {
    if (blockIdx.x == 0 && threadIdx.x == 0) {
        wsf[0] = -INFINITY; wsf[1] = 0.f;
        ((unsigned int*)wsf)[2] = 0u; ((unsigned int*)wsf)[3] = 0u;
    }
    int row  = blockIdx.x * 4 + (threadIdx.x >> 6);
    int lane = threadIdx.x & 63;
    float4 v = ((const float4*)(x + (size_t)row * DIM))[lane];
    float ss = v.x * v.x + v.y * v.y + v.z * v.z + v.w * v.w;
    #pragma unroll
    for (int off = 32; off; off >>= 1) ss += __shfl_xor(ss, off);
    float norm = fmaxf(sqrtf(ss), 1e-12f);
    float f[4] = {v.x / norm, v.y / norm, v.z / norm, v.w / norm};
    unsigned short h[4];
    #pragma unroll
    for (int j = 0; j < 4; ++j)
        h[j] = __builtin_bit_cast(unsigned short, (_Float16)f[j]);
    *(ushort4*)(a2 + (size_t)row * K2 + lane * 4) = make_ushort4(h[0], h[1], h[2], h[3]);
}

// 128x128 tile per block (lower-tri), 256 threads = 4 waves (2x2), wave-tile 64x64,
// mfma_f32_16x16x32_f16, fragments loaded DIRECTLY from global (no LDS, no barriers).
// Per k-step: lane reads 16 B of row (i0+wr*64+m*16+(lane&15)) at byte k=ks*64+(lane>>4)*16
// — logical fragment identical to the r2-r12 LDS path (absmax-0.0-verified).
// Coalescing: lanes {l,l+16,l+32,l+48} cover the full 64 B of each of 16 rows.
// Waves sharing wr (or wc) re-read the same 32 KB panel -> L1/L2 hits.
__global__ __launch_bounds__(256, 3) void sim_kernel(const unsigned short* __restrict__ a2,
                                                     float* wsf, int2* edges, int cap) {
    int bid = blockIdx.x;
    int idx = (bid & 7) * (NTRI / 8) + (bid >> 3);   // bijective XCD swizzle (2080=8*260)
    int bi = (int)((sqrtf(8.f * idx + 1.f) - 1.f) * 0.5f);
    while ((bi + 1) * (bi + 2) / 2 <= idx) ++bi;
    while (bi * (bi + 1) / 2 > idx) --bi;
    int bj = idx - bi * (bi + 1) / 2;          // bj <= bi
    int i0 = bi * 128, j0 = bj * 128;

    __shared__ float sred[12];

    int t = threadIdx.x, lane = t & 63, w = t >> 6;   // w: 0..3
    int wr = w >> 1, wc = w & 1;                       // 2x2 wave grid

    f32x4 acc[4][4] = {};

    const char* base = (const char*)a2;
    int rowA = i0 + wr * 64 + (lane & 15);             // + m*16
    int rowB = j0 + wc * 64 + (lane & 15);             // + n*16
    int koff = (lane >> 4) * 16;                       // 16B slot within 64B k-window
    const char* pA = base + (size_t)rowA * 512 + koff;
    const char* pB = base + (size_t)rowB * 512 + koff;

    #pragma unroll
    for (int ks = 0; ks < 8; ++ks) {                   // K = 256 = 8 x 32
        half8 af[4], bf[4];
        #pragma unroll
        for (int m = 0; m < 4; ++m) {
            af[m] = *(const half8*)(pA + m * (16 * 512) + ks * 64);
            bf[m] = *(const half8*)(pB + m * (16 * 512) + ks * 64);
        }
        #pragma unroll
        for (int m = 0; m < 4; ++m)
            #pragma unroll
            for (int n = 0; n < 4; ++n)
                acc[m][n] = __builtin_amdgcn_mfma_f32_16x16x32_f16(af[m], bf[n], acc[m][n], 0, 0, 0);
    }

    // fused epilogue: C/D layout col=lane&15, row=(lane>>4)*4+reg (m89-verified, r2-r12 proven)
    bool diagT = (bi == bj);
    float        wgt  = diagT ? 1.f : 2.f;
    unsigned int wgtu = diagT ? 1u : 2u;
    float lmax = -INFINITY, lsum = 0.f;
    unsigned int lcnt = 0;
    #pragma unroll
    for (int m = 0; m < 4; ++m) {
        #pragma unroll
        for (int n = 0; n < 4; ++n) {
            #pragma unroll
            for (int j = 0; j < 4; ++j) {
                float s = acc[m][n][j];
                int gi = i0 + wr * 64 + m * 16 + (lane >> 4) * 4 + j;
                int gj = j0 + wc * 64 + n * 16 + (lane & 15);
                if (gi != gj) {
                    lmax = fmaxf(lmax, s);
                    lsum += s;
                    if (s > SIM_THR) {
                        lcnt++;
                        unsigned int e = atomicAdd(&((unsigned int*)wsf)[3], 1u);
                        if (e < (unsigned int)cap) edges[e] = make_int2(gi, gj);
                    }
                }
            }
        }
    }
    #pragma unroll
    for (int off = 32; off; off >>= 1) {
        lmax = fmaxf(lmax, __shfl_xor(lmax, off));
        lsum += __shfl_xor(lsum, off);
        lcnt += __shfl_xor(lcnt, off);
    }
    if (lane == 0) { sred[w] = lmax; sred[4 + w] = lsum; ((unsigned int*)sred)[8 + w] = lcnt; }
    __syncthreads();
    if (t == 0) {
        float bm = fmaxf(fmaxf(sred[0], sred[1]), fmaxf(sred[2], sred[3]));
        float bs = sred[4] + sred[5] + sred[6] + sred[7];
        unsigned int bc = ((unsigned int*)sred)[8] + ((unsigned int*)sred)[9]
                        + ((unsigned int*)sred)[10] + ((unsigned int*)sred)[11];
        atomicMaxF(&wsf[0], bm);
        atomicAdd(&wsf[1], bs * wgt);
        if (bc) atomicAdd(&((unsigned int*)wsf)[2], bc * wgtu);
    }
}

// Single block: reference's exact 16-iter min-label + pointer-jump (LDS labels),
// early-exit when no edges (labels provably stay identity), then features + MLP.
__global__ __launch_bounds__(1024) void finalize_kernel(const float* wsf, const int2* edges, int cap,
                                                        const float* __restrict__ w1,
                                                        const float* __restrict__ b1,
                                                        const float* __restrict__ w2,
                                                        const float* __restrict__ b2,
                                                        float* __restrict__ out) {
    __shared__ int lab[NROWS];
    __shared__ int tmp[NROWS];
    __shared__ int wsum[16];
    int t = threadIdx.x;
    for (int i = t; i < NROWS; i += 1024) lab[i] = i;
    unsigned int ec = ((const unsigned int*)wsf)[3];
    if (ec > (unsigned int)cap) ec = (unsigned int)cap;
    __syncthreads();

    if (ec > 0) {
        for (int it = 0; it < 16; ++it) {   // ceil(log2(8192)) + 3 = 16, as reference
            for (int i = t; i < NROWS; i += 1024) tmp[i] = lab[i];
            __syncthreads();
            for (unsigned int e = t; e < ec; e += 1024) {
                int u = edges[e].x, v = edges[e].y;
                atomicMin(&tmp[u], lab[v]);
                atomicMin(&tmp[v], lab[u]);
            }
            __syncthreads();
            for (int i = t; i < NROWS; i += 1024) lab[i] = tmp[tmp[i]];
            __syncthreads();
        }
    }

    int lc = 0;
    for (int i = t; i < NROWS; i += 1024) lc += (lab[i] == i);
    #pragma unroll
    for (int off = 32; off; off >>= 1) lc += __shfl_xor(lc, off);
    if ((t & 63) == 0) wsum[t >> 6] = lc;
    __syncthreads();

    if (t == 0) {
        int roots = 0;
        #pragma unroll
        for (int q = 0; q < 16; ++q) roots += wsum[q];
        const float n_pairs = 67100672.0f;             // 8192*8191
        float feats[4];
        feats[0] = wsf[0];
        feats[1] = wsf[1] / n_pairs;
        feats[2] = (float)((const unsigned int*)wsf)[2] / n_pairs;
        feats[3] = (float)roots / (float)NROWS;
        float acc2 = b2[0];
        for (int j = 0; j < 16; ++j) {
            float hj = b1[j];
            #pragma unroll
            for (int i = 0; i < 4; ++i) hj = fmaf(feats[i], w1[i * 16 + j], hj);
            float g = 0.5f * hj * (1.0f + erff(hj * 0.70710678118f));
            acc2 = fmaf(g, w2[j], acc2);
        }
        out[0] = 1.0f / (1.0f + expf(-acc2));
    }
}

extern "C" void kernel_launch(void* const* d_in, const int* in_sizes, int n_in,
                              void* d_out, int out_size, void* d_ws, size_t ws_size,
                              hipStream_t stream) {
    const float* cls = (const float*)d_in[0];
    const float* w1  = (const float*)d_in[1];
    const float* b1  = (const float*)d_in[2];
    const float* w2  = (const float*)d_in[3];
    const float* b2  = (const float*)d_in[4];
    float* out = (float*)d_out;

    float* wsf = (float*)d_ws;
    unsigned short* a2 = (unsigned short*)((char*)d_ws + A2_OFF);
    int2* edges = (int2*)((char*)d_ws + EDGE_OFF);
    long long avail = (long long)ws_size - (long long)EDGE_OFF;
    int cap = (int)(avail > 0 ? (avail / 8 > 4194304 ? 4194304 : avail / 8) : 0);

    prep_kernel<<<NROWS / 4, 256, 0, stream>>>(cls, a2, wsf);
    sim_kernel<<<NTRI, 256, 0, stream>>>(a2, wsf, edges, cap);
    finalize_kernel<<<1, 1024, 0, stream>>>(wsf, edges, cap, w1, b1, w2, b2, out);
}